// Round 14
// baseline (432.671 us; speedup 1.0000x reference)
//
#include <hip/hip_runtime.h>
#include <hip/hip_bf16.h>
#include <math.h>

#define NE 64
#define NK 8
#define NH 2048
#define NI 768
#define NT 1024
#define BP 40             // bf16 col pitch within a 32-k subtile (80 B)
#define SUB64 (64 * BP)   // subtile: 64 cols x 32 k
#define SUB128 (128 * BP) // e2 subtile: 128 cols x 32 k

typedef float f32x4 __attribute__((ext_vector_type(4)));
typedef __bf16 bf16x8 __attribute__((ext_vector_type(8)));
typedef __bf16 bf16x4 __attribute__((ext_vector_type(4)));

// ---------------- router: logits (fp32), top-8, weights, x->bf16 (R6 body) ------
__global__ __launch_bounds__(256) void router_k(
    const float* __restrict__ x, const float* __restrict__ wg,
    __bf16* __restrict__ x_bf, int* __restrict__ topk_idx,
    float* __restrict__ topk_w)
{
    __shared__ float xs[4][NH];
    const int wave = threadIdx.x >> 6;
    const int lane = threadIdx.x & 63;
    const int t = blockIdx.x * 4 + wave;

    const float* xrow = x + (size_t)t * NH;
    __bf16* brow = x_bf + (size_t)t * NH;
    #pragma unroll
    for (int j = 0; j < 8; ++j) {
        int idx = j * 256 + lane * 4;
        f32x4 v = *reinterpret_cast<const f32x4*>(xrow + idx);
        *reinterpret_cast<f32x4*>(&xs[wave][idx]) = v;
        bf16x4 b;
        b[0] = (__bf16)v.x; b[1] = (__bf16)v.y; b[2] = (__bf16)v.z; b[3] = (__bf16)v.w;
        *reinterpret_cast<bf16x4*>(brow + idx) = b;
    }
    __syncthreads();

    float a0 = 0.f, a1 = 0.f, a2 = 0.f, a3 = 0.f;
    for (int h = 0; h < NH; h += 4) {
        a0 = fmaf(xs[wave][h + 0], wg[(h + 0) * NE + lane], a0);
        a1 = fmaf(xs[wave][h + 1], wg[(h + 1) * NE + lane], a1);
        a2 = fmaf(xs[wave][h + 2], wg[(h + 2) * NE + lane], a2);
        a3 = fmaf(xs[wave][h + 3], wg[(h + 3) * NE + lane], a3);
    }
    float acc = (a0 + a1) + (a2 + a3);

    float cur = acc;
    float sel_v[NK]; int sel_i[NK];
    #pragma unroll
    for (int k = 0; k < NK; ++k) {
        float bv = cur; int bi = lane;
        #pragma unroll
        for (int s = 32; s; s >>= 1) {
            float ov = __shfl_xor(bv, s, 64);
            int   oi = __shfl_xor(bi, s, 64);
            if (ov > bv || (ov == bv && oi < bi)) { bv = ov; bi = oi; }
        }
        sel_v[k] = bv; sel_i[k] = bi;
        if (lane == bi) cur = -3.4e38f;
    }
    float m = sel_v[0];
    float ssum = 0.f;
    #pragma unroll
    for (int k = 0; k < NK; ++k) ssum += expf(sel_v[k] - m);

    if (lane < NK) {
        float w = expf(sel_v[lane] - m) / ssum;
        topk_idx[t * NK + lane] = sel_i[lane];
        topk_w[t * NK + lane] = w;
    }
}

// ------- scanscatter: histogram + prefix + compacted slot lists (1 block) -------
__global__ __launch_bounds__(1024) void scanscatter_k(
    const int* __restrict__ topk_idx, const float* __restrict__ topk_w,
    int* __restrict__ counts, int* __restrict__ offs,
    int* __restrict__ slot_tok, float* __restrict__ slot_w,
    int* __restrict__ slot_of)
{
    __shared__ int hist[NE], base[NE], cur[NE];
    const int tid = threadIdx.x;
    if (tid < NE) hist[tid] = 0;
    __syncthreads();
    for (int i = tid; i < NT * NK; i += 1024)
        atomicAdd(&hist[topk_idx[i]], 1);
    __syncthreads();
    if (tid == 0) {
        int r = 0;
        for (int e = 0; e < NE; ++e) { base[e] = r; r += hist[e]; }
    }
    __syncthreads();
    if (tid < NE) { counts[tid] = hist[tid]; offs[tid] = base[tid]; cur[tid] = 0; }
    __syncthreads();
    for (int i = tid; i < NT * NK; i += 1024) {
        int e = topk_idx[i];
        int p = atomicAdd(&cur[e], 1);
        int g = base[e] + p;
        slot_tok[g] = i >> 3;
        slot_w[g] = topk_w[i];
        slot_of[i] = g;
    }
}

// ------- E1: act = silu(x@Wg)*(x@Wu); n-tile 32, 3 blk/CU, BK=64, m0-loop -------
__global__ __launch_bounds__(256, 3) void e1_k(
    const __bf16* __restrict__ x_bf, const float* __restrict__ w13,
    const int* __restrict__ counts, const int* __restrict__ offs,
    const int* __restrict__ slot_tok, __bf16* __restrict__ act)
{
    const int e = blockIdx.x;
    const int cnt = counts[e];
    const int n0 = blockIdx.y * 32;       // gate cols n0..n0+31, up cols NI+n0..
    const int eoff = offs[e];

    __shared__ __bf16 B[2][2 * SUB64];    // [buf][sub][64 cols][BP]
    __shared__ int tok[256];

    const int tid = threadIdx.x;
    const int wave = tid >> 6, lane = tid & 63;

    // B staging geometry (m0-independent)
    const float* w13e = w13 + (size_t)e * NH * (2 * NI);
    const int cc = tid & 15, kch = tid >> 4;        // col-quad 0..15, k-quad 0..15
    const int bcol0 = cc * 4;
    const int gcol = (bcol0 < 32) ? (n0 + bcol0) : (NI + n0 + bcol0 - 32);
    const int rot = (cc >> 1) & 3;
    const float* bptr = w13e + (size_t)(kch * 4) * (2 * NI) + gcol;
    const int sub = kch >> 3, kloc = kch & 7;
    int bj[4], boff[4];
    #pragma unroll
    for (int jj = 0; jj < 4; ++jj) {
        int j = (jj + rot) & 3;
        bj[jj] = j;
        boff[jj] = sub * SUB64 + (bcol0 + j) * BP + kloc * 4;
    }

    f32x4 bReg[4];
    auto loadT = [&](int kk) {
        #pragma unroll
        for (int ki = 0; ki < 4; ++ki)
            bReg[ki] = __builtin_nontemporal_load(
                reinterpret_cast<const f32x4*>(bptr + (size_t)(kk + ki) * (2 * NI)));
    };
    auto writeT = [&](int buf) {
        #pragma unroll
        for (int jj = 0; jj < 4; ++jj) {
            int j = bj[jj];
            bf16x4 p;
            p[0] = (__bf16)bReg[0][j]; p[1] = (__bf16)bReg[1][j];
            p[2] = (__bf16)bReg[2][j]; p[3] = (__bf16)bReg[3][j];
            *reinterpret_cast<bf16x4*>(&B[buf][boff[jj]]) = p;
        }
    };

    for (int m0 = 0; m0 < cnt; m0 += 256) {
        const int rows = min(256, cnt - m0);
        const int goff = eoff + m0;

        if (m0) __syncthreads();
        tok[tid] = (tid < rows) ? slot_tok[goff + tid] : slot_tok[goff];
        __syncthreads();

        f32x4 acc[4][4];                  // nf 0,1 = gate; 2,3 = up
        #pragma unroll
        for (int i = 0; i < 4; ++i)
            #pragma unroll
            for (int j = 0; j < 4; ++j) acc[i][j] = (f32x4){0.f, 0.f, 0.f, 0.f};

        const __bf16* ap[4];
        bool mok[4];
        #pragma unroll
        for (int mf = 0; mf < 4; ++mf) {
            int rf = mf * 64 + wave * 16;
            mok[mf] = (rf < rows);
            int arow = rf + (lane & 15);
            ap[mf] = x_bf + (size_t)tok[arow] * NH + ((lane >> 4) << 3);
        }

        auto compute = [&](int buf) {
            #pragma unroll
            for (int kk = 0; kk < 2; ++kk) {
                bf16x8 av[4];
                #pragma unroll
                for (int mf = 0; mf < 4; ++mf)
                    if (mok[mf]) av[mf] = *reinterpret_cast<const bf16x8*>(ap[mf] + kk * 32);
                bf16x8 bfr[4];
                #pragma unroll
                for (int nf = 0; nf < 4; ++nf) {
                    int col = nf * 16 + (lane & 15);
                    bfr[nf] = *reinterpret_cast<const bf16x8*>(
                        &B[buf][kk * SUB64 + col * BP + ((lane >> 4) << 3)]);
                }
                #pragma unroll
                for (int mf = 0; mf < 4; ++mf)
                    if (mok[mf])
                        #pragma unroll
                        for (int nf = 0; nf < 4; ++nf)
                            acc[mf][nf] = __builtin_amdgcn_mfma_f32_16x16x32_bf16(
                                av[mf], bfr[nf], acc[mf][nf], 0, 0, 0);
            }
            #pragma unroll
            for (int mf = 0; mf < 4; ++mf) ap[mf] += 64;
        };

        loadT(0);
        writeT(0);
        __syncthreads();

        #pragma unroll 1
        for (int t = 0; t < 32; ++t) {
            if (t + 1 < 32) loadT((t + 1) * 64);
            compute(t & 1);
            if (t + 1 < 32) writeT((t + 1) & 1);
            __syncthreads();
        }

        // epilogue: act = silu(gate) * up -> bf16
        #pragma unroll
        for (int mf = 0; mf < 4; ++mf) {
            int rf = mf * 64 + wave * 16;
            if (rf >= rows) continue;
            #pragma unroll
            for (int nf = 0; nf < 2; ++nf) {
                f32x4 g = acc[mf][nf];
                f32x4 u = acc[mf][nf + 2];
                int col = n0 + nf * 16 + (lane & 15);
                #pragma unroll
                for (int r = 0; r < 4; ++r) {
                    int row = rf + ((lane >> 4) << 2) + r;
                    if (row < rows) {
                        float gv = g[r];
                        float a = gv / (1.f + expf(-gv)) * u[r];
                        act[(size_t)(goff + row) * NI + col] = (__bf16)a;
                    }
                }
            }
        }
    }
}

// ------- E2: partial = w * (act@W2); n-tile 128, 2 blk/CU, m0-loop -------
__global__ __launch_bounds__(256, 2) void e2_k(
    const __bf16* __restrict__ act, const float* __restrict__ w2,
    const int* __restrict__ counts, const int* __restrict__ offs,
    const float* __restrict__ slot_w, __bf16* __restrict__ partial)
{
    const int e = blockIdx.x;
    const int cnt = counts[e];
    const int n0 = blockIdx.y * 128;
    const int eoff = offs[e];

    __shared__ __bf16 B[2][2 * SUB128];

    const int tid = threadIdx.x, wave = tid >> 6, lane = tid & 63;

    const float* w2e = w2 + (size_t)e * NI * NH;
    const int cc = tid & 31, kch = tid >> 5;
    const int bcol0 = cc * 4;
    const int rot = (cc >> 1) & 3;
    const float* bptr = w2e + (size_t)(kch * 4) * NH + n0 + bcol0;
    int bj[4], boff[4];
    #pragma unroll
    for (int jj = 0; jj < 4; ++jj) {
        int j = (jj + rot) & 3;
        bj[jj] = j;
        boff[jj] = (bcol0 + j) * BP + kch * 4;
    }

    f32x4 bReg[2][4];
    auto loadT = [&](int kk) {
        #pragma unroll
        for (int s = 0; s < 2; ++s)
            #pragma unroll
            for (int ki = 0; ki < 4; ++ki)
                bReg[s][ki] = __builtin_nontemporal_load(
                    reinterpret_cast<const f32x4*>(bptr + (size_t)(kk + s * 32 + ki) * NH));
    };
    auto writeT = [&](int buf) {
        #pragma unroll
        for (int s = 0; s < 2; ++s)
            #pragma unroll
            for (int jj = 0; jj < 4; ++jj) {
                int j = bj[jj];
                bf16x4 p;
                p[0] = (__bf16)bReg[s][0][j]; p[1] = (__bf16)bReg[s][1][j];
                p[2] = (__bf16)bReg[s][2][j]; p[3] = (__bf16)bReg[s][3][j];
                *reinterpret_cast<bf16x4*>(&B[buf][s * SUB128 + boff[jj]]) = p;
            }
    };

    for (int m0 = 0; m0 < cnt; m0 += 256) {
        const int rows = min(256, cnt - m0);
        const int goff = eoff + m0;

        f32x4 acc[4][8];
        #pragma unroll
        for (int i = 0; i < 4; ++i)
            #pragma unroll
            for (int j = 0; j < 8; ++j) acc[i][j] = (f32x4){0.f, 0.f, 0.f, 0.f};

        const __bf16* ap[4];
        bool mok[4];
        #pragma unroll
        for (int mf = 0; mf < 4; ++mf) {
            int rf = mf * 64 + wave * 16;
            mok[mf] = (rf < rows);
            int arow = goff + rf + (lane & 15);
            ap[mf] = act + (size_t)arow * NI + ((lane >> 4) << 3);
        }

        auto compute = [&](int buf) {
            #pragma unroll
            for (int kk = 0; kk < 2; ++kk) {
                bf16x8 av[4];
                #pragma unroll
                for (int mf = 0; mf < 4; ++mf)
                    if (mok[mf]) av[mf] = *reinterpret_cast<const bf16x8*>(ap[mf] + kk * 32);
                bf16x8 bfr[8];
                #pragma unroll
                for (int nf = 0; nf < 8; ++nf) {
                    int col = nf * 16 + (lane & 15);
                    bfr[nf] = *reinterpret_cast<const bf16x8*>(
                        &B[buf][kk * SUB128 + col * BP + ((lane >> 4) << 3)]);
                }
                #pragma unroll
                for (int mf = 0; mf < 4; ++mf)
                    if (mok[mf])
                        #pragma unroll
                        for (int nf = 0; nf < 8; ++nf)
                            acc[mf][nf] = __builtin_amdgcn_mfma_f32_16x16x32_bf16(
                                av[mf], bfr[nf], acc[mf][nf], 0, 0, 0);
            }
            #pragma unroll
            for (int mf = 0; mf < 4; ++mf) ap[mf] += 64;
        };

        if (m0) __syncthreads();
        loadT(0);
        writeT(0);
        __syncthreads();

        #pragma unroll 1
        for (int t = 0; t < 12; ++t) {
            if (t + 1 < 12) loadT((t + 1) * 64);
            compute(t & 1);
            if (t + 1 < 12) writeT((t + 1) & 1);
            __syncthreads();
        }

        // epilogue: partial[slot][col] = w * y  (bf16, plain stores)
        #pragma unroll
        for (int mf = 0; mf < 4; ++mf) {
            int rf = mf * 64 + wave * 16;
            if (rf >= rows) continue;
            int rb = rf + ((lane >> 4) << 2);
            #pragma unroll
            for (int r = 0; r < 4; ++r) {
                int row = rb + r;
                if (row >= rows) continue;
                int gs = goff + row;
                float wv = slot_w[gs];
                #pragma unroll
                for (int nf = 0; nf < 8; ++nf) {
                    int col = n0 + nf * 16 + (lane & 15);
                    partial[(size_t)gs * NH + col] = (__bf16)(wv * acc[mf][nf][r]);
                }
            }
        }
    }
}

// ---------------- combine: out[t] = sum_k partial[slot_of[t,k]] ----------------
__global__ __launch_bounds__(256) void combine_k(
    const __bf16* __restrict__ partial, const int* __restrict__ slot_of,
    float* __restrict__ out)
{
    const int t = blockIdx.x;
    const int c0 = threadIdx.x * 8;
    __shared__ int gs[NK];
    if (threadIdx.x < NK) gs[threadIdx.x] = slot_of[t * NK + threadIdx.x];
    __syncthreads();

    float s[8] = {0.f, 0.f, 0.f, 0.f, 0.f, 0.f, 0.f, 0.f};
    #pragma unroll
    for (int k = 0; k < NK; ++k) {
        bf16x8 v = *reinterpret_cast<const bf16x8*>(partial + (size_t)gs[k] * NH + c0);
        #pragma unroll
        for (int j = 0; j < 8; ++j) s[j] += (float)v[j];
    }
    f32x4 o0 = {s[0], s[1], s[2], s[3]};
    f32x4 o1 = {s[4], s[5], s[6], s[7]};
    *reinterpret_cast<f32x4*>(out + (size_t)t * NH + c0) = o0;
    *reinterpret_cast<f32x4*>(out + (size_t)t * NH + c0 + 4) = o1;
}

extern "C" void kernel_launch(void* const* d_in, const int* in_sizes, int n_in,
                              void* d_out, int out_size, void* d_ws, size_t ws_size,
                              hipStream_t stream)
{
    const float* x   = (const float*)d_in[0];
    const float* wg  = (const float*)d_in[1];
    const float* w13 = (const float*)d_in[2];
    const float* w2  = (const float*)d_in[3];
    float* out = (float*)d_out;
    char* ws = (char*)d_ws;

    __bf16* x_bf = (__bf16*)ws;                                    // 4 MB
    size_t o = (size_t)4 * 1024 * 1024;
    __bf16* act = (__bf16*)(ws + o);      o += (size_t)8192 * NI * 2;   // 12.58 MB
    __bf16* partial = (__bf16*)(ws + o);  o += (size_t)8192 * NH * 2;   // 33.55 MB
    int*   topk_idx = (int*)(ws + o);     o += 8192 * 4;
    float* topk_w   = (float*)(ws + o);   o += 8192 * 4;
    int*   slot_tok = (int*)(ws + o);     o += 8192 * 4;
    float* slot_w   = (float*)(ws + o);   o += 8192 * 4;
    int*   slot_of  = (int*)(ws + o);     o += 8192 * 4;
    int*   counts   = (int*)(ws + o);     o += 256;
    int*   offs     = (int*)(ws + o);     o += 256;

    router_k    <<<NT / 4, 256, 0, stream>>>(x, wg, x_bf, topk_idx, topk_w);
    scanscatter_k<<<1, 1024, 0, stream>>>(topk_idx, topk_w, counts, offs,
                                          slot_tok, slot_w, slot_of);
    e1_k<<<dim3(NE, 24), 256, 0, stream>>>(x_bf, w13, counts, offs, slot_tok, act);
    e2_k<<<dim3(NE, 16), 256, 0, stream>>>(act, w2, counts, offs, slot_w, partial);
    combine_k<<<NT, 256, 0, stream>>>(partial, slot_of, out);
}

// Round 15
// 393.377 us; speedup vs baseline: 1.0999x; 1.0999x over previous
//
#include <hip/hip_runtime.h>
#include <hip/hip_bf16.h>
#include <math.h>

#define NE 64
#define NK 8
#define NH 2048
#define NI 768
#define NT 1024
#define BP 40             // bf16 col pitch within a 32-k subtile (80 B)
#define SUB64 (64 * BP)   // subtile: 64 cols x 32 k
#define SUB128 (128 * BP) // e2 subtile: 128 cols x 32 k

typedef float f32x4 __attribute__((ext_vector_type(4)));
typedef __bf16 bf16x8 __attribute__((ext_vector_type(8)));
typedef __bf16 bf16x4 __attribute__((ext_vector_type(4)));

// ---------------- router: logits (fp32), top-8, weights, x->bf16 ----------------
__global__ __launch_bounds__(256) void router_k(
    const float* __restrict__ x, const float* __restrict__ wg,
    __bf16* __restrict__ x_bf, int* __restrict__ topk_idx,
    float* __restrict__ topk_w)
{
    __shared__ float xs[4][NH];
    const int wave = threadIdx.x >> 6;
    const int lane = threadIdx.x & 63;
    const int t = blockIdx.x * 4 + wave;

    const float* xrow = x + (size_t)t * NH;
    __bf16* brow = x_bf + (size_t)t * NH;
    #pragma unroll
    for (int j = 0; j < 8; ++j) {
        int idx = j * 256 + lane * 4;
        f32x4 v = *reinterpret_cast<const f32x4*>(xrow + idx);
        *reinterpret_cast<f32x4*>(&xs[wave][idx]) = v;
        bf16x4 b;
        b[0] = (__bf16)v.x; b[1] = (__bf16)v.y; b[2] = (__bf16)v.z; b[3] = (__bf16)v.w;
        *reinterpret_cast<bf16x4*>(brow + idx) = b;
    }
    __syncthreads();

    float a0 = 0.f, a1 = 0.f, a2 = 0.f, a3 = 0.f;
    for (int h = 0; h < NH; h += 4) {
        a0 = fmaf(xs[wave][h + 0], wg[(h + 0) * NE + lane], a0);
        a1 = fmaf(xs[wave][h + 1], wg[(h + 1) * NE + lane], a1);
        a2 = fmaf(xs[wave][h + 2], wg[(h + 2) * NE + lane], a2);
        a3 = fmaf(xs[wave][h + 3], wg[(h + 3) * NE + lane], a3);
    }
    float acc = (a0 + a1) + (a2 + a3);

    float cur = acc;
    float sel_v[NK]; int sel_i[NK];
    #pragma unroll
    for (int k = 0; k < NK; ++k) {
        float bv = cur; int bi = lane;
        #pragma unroll
        for (int s = 32; s; s >>= 1) {
            float ov = __shfl_xor(bv, s, 64);
            int   oi = __shfl_xor(bi, s, 64);
            if (ov > bv || (ov == bv && oi < bi)) { bv = ov; bi = oi; }
        }
        sel_v[k] = bv; sel_i[k] = bi;
        if (lane == bi) cur = -3.4e38f;
    }
    float m = sel_v[0];
    float ssum = 0.f;
    #pragma unroll
    for (int k = 0; k < NK; ++k) ssum += expf(sel_v[k] - m);

    if (lane < NK) {
        float w = expf(sel_v[lane] - m) / ssum;
        topk_idx[t * NK + lane] = sel_i[lane];
        topk_w[t * NK + lane] = w;
    }
}

// ------- scanscatter: histogram + prefix + compacted slot lists (1 block) -------
__global__ __launch_bounds__(1024) void scanscatter_k(
    const int* __restrict__ topk_idx, const float* __restrict__ topk_w,
    int* __restrict__ counts, int* __restrict__ offs,
    int* __restrict__ slot_tok, float* __restrict__ slot_w,
    int* __restrict__ slot_of)
{
    __shared__ int hist[NE], base[NE], cur[NE];
    const int tid = threadIdx.x;
    if (tid < NE) hist[tid] = 0;
    __syncthreads();
    for (int i = tid; i < NT * NK; i += 1024)
        atomicAdd(&hist[topk_idx[i]], 1);
    __syncthreads();
    if (tid == 0) {
        int r = 0;
        for (int e = 0; e < NE; ++e) { base[e] = r; r += hist[e]; }
    }
    __syncthreads();
    if (tid < NE) { counts[tid] = hist[tid]; offs[tid] = base[tid]; cur[tid] = 0; }
    __syncthreads();
    for (int i = tid; i < NT * NK; i += 1024) {
        int e = topk_idx[i];
        int p = atomicAdd(&cur[e], 1);
        int g = base[e] + p;
        slot_tok[g] = i >> 3;
        slot_w[g] = topk_w[i];
        slot_of[i] = g;
    }
}

// --- E1: act = silu(x@Wg)*(x@Wu); n-tile 32, 3 blk/CU, BK=64, depth-2 B pipe ---
__global__ __launch_bounds__(256, 3) void e1_k(
    const __bf16* __restrict__ x_bf, const float* __restrict__ w13,
    const int* __restrict__ counts, const int* __restrict__ offs,
    const int* __restrict__ slot_tok, __bf16* __restrict__ act)
{
    const int e = blockIdx.x;
    const int cnt = counts[e];
    const int m0 = blockIdx.z * 256;
    if (m0 >= cnt) return;
    const int rows = min(256, cnt - m0);
    const int n0 = blockIdx.y * 32;       // gate cols n0..n0+31, up cols NI+n0..
    const int goff = offs[e] + m0;

    __shared__ __bf16 B[2][2 * SUB64];    // [buf][sub][64 cols][BP]
    __shared__ int tok[256];

    const int tid = threadIdx.x;
    tok[tid] = (tid < rows) ? slot_tok[goff + tid] : slot_tok[goff];
    __syncthreads();

    const int wave = tid >> 6, lane = tid & 63;
    f32x4 acc[4][4];                      // nf 0,1 = gate; 2,3 = up
    #pragma unroll
    for (int i = 0; i < 4; ++i)
        #pragma unroll
        for (int j = 0; j < 4; ++j) acc[i][j] = (f32x4){0.f, 0.f, 0.f, 0.f};

    // A: direct global fragments (L2/L3-resident x_bf)
    const __bf16* ap[4];
    bool mok[4];
    #pragma unroll
    for (int mf = 0; mf < 4; ++mf) {
        int rf = mf * 64 + wave * 16;
        mok[mf] = (rf < rows);
        int arow = rf + (lane & 15);
        ap[mf] = x_bf + (size_t)tok[arow] * NH + ((lane >> 4) << 3);
    }

    // B staging: 64 cols (32 gate + 32 up) x 64 k per step
    const float* w13e = w13 + (size_t)e * NH * (2 * NI);
    const int cc = tid & 15, kch = tid >> 4;        // col-quad 0..15, k-quad 0..15
    const int bcol0 = cc * 4;
    const int gcol = (bcol0 < 32) ? (n0 + bcol0) : (NI + n0 + bcol0 - 32);
    const int rot = (cc >> 1) & 3;
    const float* bptr = w13e + (size_t)(kch * 4) * (2 * NI) + gcol;
    const int sub = kch >> 3, kloc = kch & 7;
    int bj[4], boff[4];
    #pragma unroll
    for (int jj = 0; jj < 4; ++jj) {
        int j = (jj + rot) & 3;
        bj[jj] = j;
        boff[jj] = sub * SUB64 + (bcol0 + j) * BP + kloc * 4;
    }

    // two named B register sets -> depth-2 prefetch (counted vmcnt at writeT)
    f32x4 bR0[4], bR1[4];
    auto loadTo = [&](f32x4* dst, int kk) {
        #pragma unroll
        for (int ki = 0; ki < 4; ++ki)
            dst[ki] = __builtin_nontemporal_load(
                reinterpret_cast<const f32x4*>(bptr + (size_t)(kk + ki) * (2 * NI)));
    };
    auto writeT = [&](int buf, const f32x4* src) {
        #pragma unroll
        for (int jj = 0; jj < 4; ++jj) {
            int j = bj[jj];
            bf16x4 p;
            p[0] = (__bf16)src[0][j]; p[1] = (__bf16)src[1][j];
            p[2] = (__bf16)src[2][j]; p[3] = (__bf16)src[3][j];
            *reinterpret_cast<bf16x4*>(&B[buf][boff[jj]]) = p;
        }
    };
    auto compute = [&](int buf) {
        #pragma unroll
        for (int kk = 0; kk < 2; ++kk) {
            bf16x8 av[4];
            #pragma unroll
            for (int mf = 0; mf < 4; ++mf)
                if (mok[mf]) av[mf] = *reinterpret_cast<const bf16x8*>(ap[mf] + kk * 32);
            bf16x8 bfr[4];
            #pragma unroll
            for (int nf = 0; nf < 4; ++nf) {
                int col = nf * 16 + (lane & 15);
                bfr[nf] = *reinterpret_cast<const bf16x8*>(
                    &B[buf][kk * SUB64 + col * BP + ((lane >> 4) << 3)]);
            }
            #pragma unroll
            for (int mf = 0; mf < 4; ++mf)
                if (mok[mf])
                    #pragma unroll
                    for (int nf = 0; nf < 4; ++nf)
                        acc[mf][nf] = __builtin_amdgcn_mfma_f32_16x16x32_bf16(
                            av[mf], bfr[nf], acc[mf][nf], 0, 0, 0);
        }
        #pragma unroll
        for (int mf = 0; mf < 4; ++mf) ap[mf] += 64;
    };

    // prologue: k-steps 0 and 1 in flight; step 0 -> LDS buf0
    loadTo(bR0, 0);
    loadTo(bR1, 64);
    writeT(0, bR0);
    __syncthreads();

    #pragma unroll 1
    for (int t = 0; t < 32; t += 2) {
        if (t + 2 < 32) loadTo(bR0, (t + 2) * 64);   // issue step t+2
        compute(0);                                   // consume step t
        writeT(1, bR1);                               // stage step t+1 (counted wait)
        __syncthreads();
        if (t + 3 < 32) loadTo(bR1, (t + 3) * 64);   // issue step t+3
        compute(1);                                   // consume step t+1
        if (t + 2 < 32) writeT(0, bR0);               // stage step t+2
        __syncthreads();
    }

    // epilogue: act = silu(gate) * up -> bf16
    #pragma unroll
    for (int mf = 0; mf < 4; ++mf) {
        int rf = mf * 64 + wave * 16;
        if (rf >= rows) continue;
        #pragma unroll
        for (int nf = 0; nf < 2; ++nf) {
            f32x4 g = acc[mf][nf];
            f32x4 u = acc[mf][nf + 2];
            int col = n0 + nf * 16 + (lane & 15);
            #pragma unroll
            for (int r = 0; r < 4; ++r) {
                int row = rf + ((lane >> 4) << 2) + r;
                if (row < rows) {
                    float gv = g[r];
                    float a = gv / (1.f + expf(-gv)) * u[r];
                    act[(size_t)(goff + row) * NI + col] = (__bf16)a;
                }
            }
        }
    }
}

// ------- E2: partial = w * (act@W2); n-tile 128, 2 blk/CU (R6 exact) -------
__global__ __launch_bounds__(256, 2) void e2_k(
    const __bf16* __restrict__ act, const float* __restrict__ w2,
    const int* __restrict__ counts, const int* __restrict__ offs,
    const float* __restrict__ slot_w, __bf16* __restrict__ partial)
{
    const int e = blockIdx.x;
    const int cnt = counts[e];
    const int m0 = blockIdx.z * 256;
    if (m0 >= cnt) return;
    const int rows = min(256, cnt - m0);
    const int n0 = blockIdx.y * 128;
    const int goff = offs[e] + m0;

    __shared__ __bf16 B[2][2 * SUB128];

    const int tid = threadIdx.x, wave = tid >> 6, lane = tid & 63;
    f32x4 acc[4][8];
    #pragma unroll
    for (int i = 0; i < 4; ++i)
        #pragma unroll
        for (int j = 0; j < 8; ++j) acc[i][j] = (f32x4){0.f, 0.f, 0.f, 0.f};

    const __bf16* ap[4];
    bool mok[4];
    #pragma unroll
    for (int mf = 0; mf < 4; ++mf) {
        int rf = mf * 64 + wave * 16;
        mok[mf] = (rf < rows);
        int arow = goff + rf + (lane & 15);
        ap[mf] = act + (size_t)arow * NI + ((lane >> 4) << 3);
    }

    const float* w2e = w2 + (size_t)e * NI * NH;
    const int cc = tid & 31, kch = tid >> 5;
    const int bcol0 = cc * 4;
    const int rot = (cc >> 1) & 3;
    const float* bptr = w2e + (size_t)(kch * 4) * NH + n0 + bcol0;
    int bj[4], boff[4];
    #pragma unroll
    for (int jj = 0; jj < 4; ++jj) {
        int j = (jj + rot) & 3;
        bj[jj] = j;
        boff[jj] = (bcol0 + j) * BP + kch * 4;
    }

    f32x4 bReg[2][4];
    auto loadT = [&](int kk) {
        #pragma unroll
        for (int s = 0; s < 2; ++s)
            #pragma unroll
            for (int ki = 0; ki < 4; ++ki)
                bReg[s][ki] = __builtin_nontemporal_load(
                    reinterpret_cast<const f32x4*>(bptr + (size_t)(kk + s * 32 + ki) * NH));
    };
    auto writeT = [&](int buf) {
        #pragma unroll
        for (int s = 0; s < 2; ++s)
            #pragma unroll
            for (int jj = 0; jj < 4; ++jj) {
                int j = bj[jj];
                bf16x4 p;
                p[0] = (__bf16)bReg[s][0][j]; p[1] = (__bf16)bReg[s][1][j];
                p[2] = (__bf16)bReg[s][2][j]; p[3] = (__bf16)bReg[s][3][j];
                *reinterpret_cast<bf16x4*>(&B[buf][s * SUB128 + boff[jj]]) = p;
            }
    };
    auto compute = [&](int buf) {
        #pragma unroll
        for (int kk = 0; kk < 2; ++kk) {
            bf16x8 av[4];
            #pragma unroll
            for (int mf = 0; mf < 4; ++mf)
                if (mok[mf]) av[mf] = *reinterpret_cast<const bf16x8*>(ap[mf] + kk * 32);
            bf16x8 bfr[8];
            #pragma unroll
            for (int nf = 0; nf < 8; ++nf) {
                int col = nf * 16 + (lane & 15);
                bfr[nf] = *reinterpret_cast<const bf16x8*>(
                    &B[buf][kk * SUB128 + col * BP + ((lane >> 4) << 3)]);
            }
            #pragma unroll
            for (int mf = 0; mf < 4; ++mf)
                if (mok[mf])
                    #pragma unroll
                    for (int nf = 0; nf < 8; ++nf)
                        acc[mf][nf] = __builtin_amdgcn_mfma_f32_16x16x32_bf16(
                            av[mf], bfr[nf], acc[mf][nf], 0, 0, 0);
        }
        #pragma unroll
        for (int mf = 0; mf < 4; ++mf) ap[mf] += 64;
    };

    loadT(0);
    writeT(0);
    __syncthreads();

    #pragma unroll 1
    for (int t = 0; t < 12; ++t) {
        if (t + 1 < 12) loadT((t + 1) * 64);
        compute(t & 1);
        if (t + 1 < 12) writeT((t + 1) & 1);
        __syncthreads();
    }

    // epilogue: partial[slot][col] = w * y  (bf16, plain stores)
    #pragma unroll
    for (int mf = 0; mf < 4; ++mf) {
        int rf = mf * 64 + wave * 16;
        if (rf >= rows) continue;
        int rb = rf + ((lane >> 4) << 2);
        #pragma unroll
        for (int r = 0; r < 4; ++r) {
            int row = rb + r;
            if (row >= rows) continue;
            int gs = goff + row;
            float wv = slot_w[gs];
            #pragma unroll
            for (int nf = 0; nf < 8; ++nf) {
                int col = n0 + nf * 16 + (lane & 15);
                partial[(size_t)gs * NH + col] = (__bf16)(wv * acc[mf][nf][r]);
            }
        }
    }
}

// ---------------- combine: out[t] = sum_k partial[slot_of[t,k]] ----------------
__global__ __launch_bounds__(256) void combine_k(
    const __bf16* __restrict__ partial, const int* __restrict__ slot_of,
    float* __restrict__ out)
{
    const int t = blockIdx.x;
    const int c0 = threadIdx.x * 8;
    __shared__ int gs[NK];
    if (threadIdx.x < NK) gs[threadIdx.x] = slot_of[t * NK + threadIdx.x];
    __syncthreads();

    float s[8] = {0.f, 0.f, 0.f, 0.f, 0.f, 0.f, 0.f, 0.f};
    #pragma unroll
    for (int k = 0; k < NK; ++k) {
        bf16x8 v = *reinterpret_cast<const bf16x8*>(partial + (size_t)gs[k] * NH + c0);
        #pragma unroll
        for (int j = 0; j < 8; ++j) s[j] += (float)v[j];
    }
    f32x4 o0 = {s[0], s[1], s[2], s[3]};
    f32x4 o1 = {s[4], s[5], s[6], s[7]};
    *reinterpret_cast<f32x4*>(out + (size_t)t * NH + c0) = o0;
    *reinterpret_cast<f32x4*>(out + (size_t)t * NH + c0 + 4) = o1;
}

extern "C" void kernel_launch(void* const* d_in, const int* in_sizes, int n_in,
                              void* d_out, int out_size, void* d_ws, size_t ws_size,
                              hipStream_t stream)
{
    const float* x   = (const float*)d_in[0];
    const float* wg  = (const float*)d_in[1];
    const float* w13 = (const float*)d_in[2];
    const float* w2  = (const float*)d_in[3];
    float* out = (float*)d_out;
    char* ws = (char*)d_ws;

    __bf16* x_bf = (__bf16*)ws;                                    // 4 MB
    size_t o = (size_t)4 * 1024 * 1024;
    __bf16* act = (__bf16*)(ws + o);      o += (size_t)8192 * NI * 2;   // 12.58 MB
    __bf16* partial = (__bf16*)(ws + o);  o += (size_t)8192 * NH * 2;   // 33.55 MB
    int*   topk_idx = (int*)(ws + o);     o += 8192 * 4;
    float* topk_w   = (float*)(ws + o);   o += 8192 * 4;
    int*   slot_tok = (int*)(ws + o);     o += 8192 * 4;
    float* slot_w   = (float*)(ws + o);   o += 8192 * 4;
    int*   slot_of  = (int*)(ws + o);     o += 8192 * 4;
    int*   counts   = (int*)(ws + o);     o += 256;
    int*   offs     = (int*)(ws + o);     o += 256;

    router_k    <<<NT / 4, 256, 0, stream>>>(x, wg, x_bf, topk_idx, topk_w);
    scanscatter_k<<<1, 1024, 0, stream>>>(topk_idx, topk_w, counts, offs,
                                          slot_tok, slot_w, slot_of);
    e1_k<<<dim3(NE, 24, 2), 256, 0, stream>>>(x_bf, w13, counts, offs, slot_tok, act);
    e2_k<<<dim3(NE, 16, 2), 256, 0, stream>>>(act, w2, counts, offs, slot_w, partial);
    combine_k<<<NT, 256, 0, stream>>>(partial, slot_of, out);
}